// Round 3
// baseline (266.284 us; speedup 1.0000x reference)
//
#include <hip/hip_runtime.h>
#include <math.h>

// Problem constants (reference: B=2, S=T=400, D=512)
#define BB 2
#define SS 400
#define DD 512
#define TWO_LOG2E 2.8853900817779268f   // tanh(x) = 1 - 2/(exp2(TWO_LOG2E*x)+1)

#if __has_builtin(__builtin_amdgcn_exp2f)
#define EXP2F(x) __builtin_amdgcn_exp2f(x)
#else
#define EXP2F(x) exp2f(x)
#endif
#define RCPF(x) __builtin_amdgcn_rcpf(x)

// Workspace float layout:
//   buf0 [0,        409600) : split-K accumulated input@Wq      [B,S,D] (atomic)
//   buf1 [409600,   819200) : split-K accumulated mb@Wc         [B,S,D] (atomic)
//   M    [819200,  1228800) : split-K accumulated mb@Wout_top   [B,S,D] (atomic)
//   ta   [1228800, 1638400) : tanh(buf0 + bq)                   [B,S,D]
//   tbT  [1638400, 2048000) : tanh(buf1) transposed             [B,D,S]
// out0 pre-initialized with bout by k0; k1 m==3 atomically adds input@Wout_bot.
#define BUF0 0
#define BUF1 409600
#define MOFF 819200
#define TAOFF 1228800
#define TBTOFF 1638400

__device__ __forceinline__ float tanh_fast(float x) {
    return fmaf(-2.f, RCPF(EXP2F(TWO_LOG2E * x) + 1.f), 1.f);
}

// ---------------------------------------------------------------------------
// K0: out0[t,b,d] = bout[d]  (atomic base for k1 m==3 and k3)
// ---------------------------------------------------------------------------
__global__ __launch_bounds__(256) void k0_init(
    const float* __restrict__ bout, float* __restrict__ out0)
{
    const int i4 = blockIdx.x * 256 + threadIdx.x;      // 0..102399
    const float4 bb = ((const float4*)bout)[i4 & 127];
    ((float4*)out0)[i4] = bb;
}

// ---------------------------------------------------------------------------
// K1: four GEMMs (800x512x512), split-K x4, atomic fp32 accumulation.
// Block: 256 thr = 16 rows x 512 cols; thread = 8 rows x 4 cols (float4).
// A reads wave-uniform (readfirstlane -> s_load_dwordx4), W reads dwordx4.
// Grid (50 rowgroups, 4 kchunks, 4 gemms).
// ---------------------------------------------------------------------------
__global__ __launch_bounds__(256) void k1_gemm(
    const float* __restrict__ input, const float* __restrict__ mb,
    const float* __restrict__ Wq, const float* __restrict__ Wc,
    const float* __restrict__ Wout, float* __restrict__ ws,
    float* __restrict__ out0)
{
    const int q    = threadIdx.x & 127;
    const int half = threadIdx.x >> 7;                 // wave-uniform
    const int d0   = q * 4;
    const int m    = blockIdx.z;
    const int k0   = blockIdx.y * 128;
    const int r0   = __builtin_amdgcn_readfirstlane(blockIdx.x * 16 + half * 8);

    const float* __restrict__ A;
    const float* __restrict__ W;
    if (m == 0)      { A = input; W = Wq; }
    else if (m == 1) { A = mb;    W = Wc; }
    else if (m == 2) { A = mb;    W = Wout; }
    else             { A = input; W = Wout + DD * DD; }

    const float* __restrict__ Ap = A + (size_t)r0 * DD + k0;
    const float* __restrict__ Wp = W + (size_t)k0 * DD + d0;

    float4 acc[8];
    #pragma unroll
    for (int r = 0; r < 8; ++r) acc[r] = make_float4(0.f, 0.f, 0.f, 0.f);

    for (int e = 0; e < 128; e += 4) {
        const float4 w0 = *(const float4*)(Wp + (size_t)(e + 0) * DD);
        const float4 w1 = *(const float4*)(Wp + (size_t)(e + 1) * DD);
        const float4 w2 = *(const float4*)(Wp + (size_t)(e + 2) * DD);
        const float4 w3 = *(const float4*)(Wp + (size_t)(e + 3) * DD);
        #pragma unroll
        for (int r = 0; r < 8; ++r) {
            const float4 ar = *(const float4*)(Ap + (size_t)r * DD + e);
            acc[r].x = fmaf(ar.x, w0.x, acc[r].x);
            acc[r].y = fmaf(ar.x, w0.y, acc[r].y);
            acc[r].z = fmaf(ar.x, w0.z, acc[r].z);
            acc[r].w = fmaf(ar.x, w0.w, acc[r].w);
            acc[r].x = fmaf(ar.y, w1.x, acc[r].x);
            acc[r].y = fmaf(ar.y, w1.y, acc[r].y);
            acc[r].z = fmaf(ar.y, w1.z, acc[r].z);
            acc[r].w = fmaf(ar.y, w1.w, acc[r].w);
            acc[r].x = fmaf(ar.z, w2.x, acc[r].x);
            acc[r].y = fmaf(ar.z, w2.y, acc[r].y);
            acc[r].z = fmaf(ar.z, w2.z, acc[r].z);
            acc[r].w = fmaf(ar.z, w2.w, acc[r].w);
            acc[r].x = fmaf(ar.w, w3.x, acc[r].x);
            acc[r].y = fmaf(ar.w, w3.y, acc[r].y);
            acc[r].z = fmaf(ar.w, w3.z, acc[r].z);
            acc[r].w = fmaf(ar.w, w3.w, acc[r].w);
        }
    }

    if (m == 3) {
        const int b  = (r0 >= SS) ? 1 : 0;
        const int tb = r0 - b * SS;
        #pragma unroll
        for (int r = 0; r < 8; ++r) {
            float* p = out0 + ((size_t)((tb + r) * BB + b)) * DD + d0;
            unsafeAtomicAdd(p + 0, acc[r].x);
            unsafeAtomicAdd(p + 1, acc[r].y);
            unsafeAtomicAdd(p + 2, acc[r].z);
            unsafeAtomicAdd(p + 3, acc[r].w);
        }
    } else {
        float* __restrict__ dst = ws + (m == 0 ? BUF0 : m == 1 ? BUF1 : MOFF);
        #pragma unroll
        for (int r = 0; r < 8; ++r) {
            float* p = dst + (size_t)(r0 + r) * DD + d0;
            unsafeAtomicAdd(p + 0, acc[r].x);
            unsafeAtomicAdd(p + 1, acc[r].y);
            unsafeAtomicAdd(p + 2, acc[r].z);
            unsafeAtomicAdd(p + 3, acc[r].w);
        }
    }
}

// ---------------------------------------------------------------------------
// K1R_ta: ta = tanh(buf0 + bq), elementwise float4.
// ---------------------------------------------------------------------------
__global__ __launch_bounds__(256) void k1r_ta(
    const float* __restrict__ ws_buf0, const float* __restrict__ bq,
    float* __restrict__ ta)
{
    const int i4 = blockIdx.x * 256 + threadIdx.x;   // 0..102399
    const float4 x = ((const float4*)ws_buf0)[i4];
    const float4 bb = ((const float4*)bq)[i4 & 127];
    float4 r;
    r.x = tanh_fast(x.x + bb.x);
    r.y = tanh_fast(x.y + bb.y);
    r.z = tanh_fast(x.z + bb.z);
    r.w = tanh_fast(x.w + bb.w);
    ((float4*)ta)[i4] = r;
}

// ---------------------------------------------------------------------------
// K1R_tb: tbT[b][e][s] = tanh(buf1[b][s][e]) via 32x32 LDS tiles.
// Grid 2*16*13 = 416 blocks.
// ---------------------------------------------------------------------------
__global__ __launch_bounds__(256) void k1r_tb(
    const float* __restrict__ ws_buf1, float* __restrict__ tbT)
{
    const int idx = blockIdx.x;
    const int b   = idx / 208;
    const int rem = idx - b * 208;
    const int et  = rem / 13;
    const int st  = rem - et * 13;
    const int e0  = et * 32;
    const int s0  = st * 32;

    __shared__ float tile[32][33];
    const int col  = threadIdx.x & 31;
    const int row0 = threadIdx.x >> 5;

    #pragma unroll
    for (int k = 0; k < 4; ++k) {
        const int sl = row0 + 8 * k;
        const int s  = s0 + sl;
        if (s < SS)
            tile[sl][col] = tanh_fast(ws_buf1[((size_t)b * SS + s) * DD + e0 + col]);
    }
    __syncthreads();
    #pragma unroll
    for (int k = 0; k < 4; ++k) {
        const int el = row0 + 8 * k;
        const int s  = s0 + col;
        if (s < SS)
            tbT[((size_t)b * DD + e0 + el) * SS + s] = tile[col][el];
    }
}

// ---------------------------------------------------------------------------
// K2: tanh-identity scores + dual softmax. Block = (b, t-pair), 448 thr = s.
// score(t,s) = sum_e v[e] * (ta[t][e]+tbT[e][s]) / (1 + ta[t][e]*tbT[e][s])
// tbT per-lane coalesced dword; ta/v uniform scalar loads.
// ---------------------------------------------------------------------------
__global__ __launch_bounds__(448) void k2_attn(
    const float* __restrict__ ws, const float* __restrict__ v,
    const int* __restrict__ lens, float* __restrict__ align_out)
{
    const int pair = blockIdx.x;           // 0..399
    const int b    = pair / 200;
    const int t0   = (pair - b * 200) * 2;
    const int t1   = t0 + 1;
    const int tid  = threadIdx.x;
    const int s    = tid;
    const int sidx = (s < SS) ? s : 0;
    const int len  = lens[b];

    const float* __restrict__ tb  = ws + TBTOFF + (size_t)b * DD * SS;
    const float* __restrict__ ta0 = ws + TAOFF + ((size_t)b * SS + t0) * DD;
    const float* __restrict__ ta1 = ta0 + DD;

    float accA0 = 0.f, accB0 = 0.f, accA1 = 0.f, accB1 = 0.f;
    for (int e = 0; e < DD; e += 4) {
        #pragma unroll
        for (int u = 0; u < 4; ++u) {
            const float tbv = tb[(size_t)(e + u) * SS + sidx];
            const float a0  = ta0[e + u];
            const float a1  = ta1[e + u];
            const float vv  = v[e + u];
            const float n0  = a0 + tbv;
            const float n1  = a1 + tbv;
            const float r0  = RCPF(fmaf(a0, tbv, 1.f));
            const float r1  = RCPF(fmaf(a1, tbv, 1.f));
            if (u & 1) {
                accB0 = fmaf(vv, n0 * r0, accB0);
                accB1 = fmaf(vv, n1 * r1, accB1);
            } else {
                accA0 = fmaf(vv, n0 * r0, accA0);
                accA1 = fmaf(vv, n1 * r1, accA1);
            }
        }
    }

    const bool v0 = (s < SS) && (s < len) && (s != t0);
    const bool v1 = (s < SS) && (s < len) && (s != t1);
    const float sc0 = v0 ? (accA0 + accB0) : -INFINITY;
    const float sc1 = v1 ? (accA1 + accB1) : -INFINITY;

    __shared__ float wred0[8], wred1[8];
    const int wid  = tid >> 6;
    const int lane = tid & 63;

    float m0 = sc0, m1 = sc1;
    #pragma unroll
    for (int off = 32; off > 0; off >>= 1) {
        m0 = fmaxf(m0, __shfl_xor(m0, off));
        m1 = fmaxf(m1, __shfl_xor(m1, off));
    }
    if (lane == 0) { wred0[wid] = m0; wred1[wid] = m1; }
    __syncthreads();
    float mx0 = wred0[0], mx1 = wred1[0];
    #pragma unroll
    for (int w = 1; w < 7; ++w) {
        mx0 = fmaxf(mx0, wred0[w]);
        mx1 = fmaxf(mx1, wred1[w]);
    }
    __syncthreads();

    const float p0 = v0 ? __expf(sc0 - mx0) : 0.f;
    const float p1 = v1 ? __expf(sc1 - mx1) : 0.f;
    float s0v = p0, s1v = p1;
    #pragma unroll
    for (int off = 32; off > 0; off >>= 1) {
        s0v += __shfl_xor(s0v, off);
        s1v += __shfl_xor(s1v, off);
    }
    if (lane == 0) { wred0[wid] = s0v; wred1[wid] = s1v; }
    __syncthreads();
    float tot0 = wred0[0], tot1 = wred1[0];
    #pragma unroll
    for (int w = 1; w < 7; ++w) { tot0 += wred0[w]; tot1 += wred1[w]; }
    const float inv0 = RCPF(tot0);
    const float inv1 = RCPF(tot1);

    if (s < SS) {
        align_out[((size_t)(t0 * BB) + b) * SS + s] = p0 * inv0;
        align_out[((size_t)(t1 * BB) + b) * SS + s] = p1 * inv1;
    }
}

// ---------------------------------------------------------------------------
// K3: out0[t,b,d] += sum_{s chunk} align[t,b,s] * M[b,s,d]; s unrolled x4,
// align via uniform s_load_dwordx4. Grid (2,100,4) = 800 blocks.
// ---------------------------------------------------------------------------
__global__ __launch_bounds__(256) void k3_out(
    const float* __restrict__ ws, const float* __restrict__ align_out,
    float* __restrict__ out0)
{
    const int d     = blockIdx.x * 256 + threadIdx.x;
    const int r0    = blockIdx.y * 8;
    const int s0    = blockIdx.z * 100;
    const int b     = (r0 >= SS) ? 1 : 0;
    const int tbase = r0 - b * SS;

    const float* __restrict__ Mb = ws + MOFF + (size_t)b * SS * DD;

    float acc[8];
    #pragma unroll
    for (int j = 0; j < 8; ++j) acc[j] = 0.f;

    for (int s = s0; s < s0 + 100; s += 4) {
        float4 al[8];
        #pragma unroll
        for (int j = 0; j < 8; ++j)
            al[j] = *(const float4*)(align_out + ((size_t)((tbase + j) * BB) + b) * SS + s);
        const float mv0 = Mb[(size_t)(s + 0) * DD + d];
        const float mv1 = Mb[(size_t)(s + 1) * DD + d];
        const float mv2 = Mb[(size_t)(s + 2) * DD + d];
        const float mv3 = Mb[(size_t)(s + 3) * DD + d];
        #pragma unroll
        for (int j = 0; j < 8; ++j) {
            acc[j] = fmaf(al[j].x, mv0, acc[j]);
            acc[j] = fmaf(al[j].y, mv1, acc[j]);
            acc[j] = fmaf(al[j].z, mv2, acc[j]);
            acc[j] = fmaf(al[j].w, mv3, acc[j]);
        }
    }

    #pragma unroll
    for (int j = 0; j < 8; ++j)
        unsafeAtomicAdd(&out0[((size_t)((tbase + j) * BB) + b) * DD + d], acc[j]);
}

// ---------------------------------------------------------------------------
extern "C" void kernel_launch(void* const* d_in, const int* in_sizes, int n_in,
                              void* d_out, int out_size, void* d_ws, size_t ws_size,
                              hipStream_t stream)
{
    const float* input = (const float*)d_in[0];
    const float* mb    = (const float*)d_in[1];
    const int*   lens  = (const int*)d_in[2];
    const float* Wq    = (const float*)d_in[3];
    const float* bq    = (const float*)d_in[4];
    const float* Wc    = (const float*)d_in[5];
    const float* v     = (const float*)d_in[6];
    const float* Wout  = (const float*)d_in[7];
    const float* bout  = (const float*)d_in[8];

    float* out0 = (float*)d_out;               // [T,B,D] = 409600
    float* out1 = out0 + (size_t)BB * SS * DD; // [T,B,S] = 320000
    float* ws   = (float*)d_ws;

    // zero split-K accumulators buf0,buf1,M (contiguous 1228800 floats)
    hipMemsetAsync(ws, 0, (size_t)1228800 * sizeof(float), stream);

    hipLaunchKernelGGL(k0_init, dim3(400), dim3(256), 0, stream, bout, out0);
    hipLaunchKernelGGL(k1_gemm, dim3(50, 4, 4), dim3(256), 0, stream,
                       input, mb, Wq, Wc, Wout, ws, out0);
    hipLaunchKernelGGL(k1r_ta, dim3(400), dim3(256), 0, stream,
                       ws + BUF0, bq, ws + TAOFF);
    hipLaunchKernelGGL(k1r_tb, dim3(416), dim3(256), 0, stream,
                       ws + BUF1, ws + TBTOFF);
    hipLaunchKernelGGL(k2_attn, dim3(400), dim3(448), 0, stream,
                       ws, v, lens, out1);
    hipLaunchKernelGGL(k3_out, dim3(2, 100, 4), dim3(256), 0, stream,
                       ws, out1, out0);
}

// Round 4
// 217.115 us; speedup vs baseline: 1.2265x; 1.2265x over previous
//
#include <hip/hip_runtime.h>
#include <math.h>

// Problem constants (reference: B=2, S=T=400, D=512)
#define BB 2
#define SS 400
#define DD 512
#define TWO_LOG2E 2.8853900817779268f   // tanh(x) = 1 - 2/(exp2(TWO_LOG2E*x)+1)

#if __has_builtin(__builtin_amdgcn_exp2f)
#define EXP2F(x) __builtin_amdgcn_exp2f(x)
#else
#define EXP2F(x) exp2f(x)
#endif
#define RCPF(x) __builtin_amdgcn_rcpf(x)

// Workspace float layout:
//   ta   [0,       409600) : tanh(input@Wq + bq)                    [B,T,D]
//   M    [409600,  819200) : mb@Wout_top                            [B,S,D]
//   tbT4 [819200, 1228800) : tanh(mb@Wc), packed [B][D/4][S] float4
// out0 initialized with input@Wout_bot + bout by k1 (m==3); k3 atomically adds context.
#define TAOFF 0
#define MOFF 409600
#define TBT4OFF 819200

__device__ __forceinline__ float tanh_fast(float x) {
    return fmaf(-2.f, RCPF(EXP2F(TWO_LOG2E * x) + 1.f), 1.f);
}

// ---------------------------------------------------------------------------
// K1: four GEMMs (800x512x512), full K per block (fused epilogues, no atomics).
// Grid (50 rowgroups x 4 colgroups x 4 gemms) = 800 blocks, 256 thr.
// Block tile: 16 rows x 128 cols; thread = 2 rows x 4 cols (float4).
// W loads coalesced dwordx4; A loads wave-broadcast (L1 hit).
// Epilogues: m0 -> ta = tanh(acc+bq); m1 -> tbT4 (transposed float4-packed
// tanh); m2 -> M; m3 -> out0 = acc + bout ([T,B,D]).
// ---------------------------------------------------------------------------
__global__ __launch_bounds__(256) void k1_gemm(
    const float* __restrict__ input, const float* __restrict__ mb,
    const float* __restrict__ Wq, const float* __restrict__ bq,
    const float* __restrict__ Wc, const float* __restrict__ Wout,
    const float* __restrict__ bout, float* __restrict__ ws,
    float* __restrict__ out0)
{
    const int q    = threadIdx.x & 31;
    const int rg   = threadIdx.x >> 5;               // 0..7
    const int d0   = blockIdx.y * 128 + q * 4;       // output col (0..508)
    const int r0   = blockIdx.x * 16;                // row base of block
    const int m    = blockIdx.z;
    const int row0 = r0 + rg * 2;                    // this thread's first row

    const float* __restrict__ A = (m == 0 || m == 3) ? input : mb;
    const float* __restrict__ W =
        (m == 0) ? Wq : (m == 1) ? Wc : (m == 2) ? Wout : Wout + DD * DD;

    const float* __restrict__ Ap0 = A + (size_t)row0 * DD;
    const float* __restrict__ Ap1 = Ap0 + DD;
    const float* __restrict__ Wp  = W + d0;

    float4 acc0 = make_float4(0.f, 0.f, 0.f, 0.f);
    float4 acc1 = make_float4(0.f, 0.f, 0.f, 0.f);

    for (int e = 0; e < DD; e += 4) {
        const float4 w0 = *(const float4*)(Wp + (size_t)(e + 0) * DD);
        const float4 w1 = *(const float4*)(Wp + (size_t)(e + 1) * DD);
        const float4 w2 = *(const float4*)(Wp + (size_t)(e + 2) * DD);
        const float4 w3 = *(const float4*)(Wp + (size_t)(e + 3) * DD);
        const float4 a0 = *(const float4*)(Ap0 + e);
        const float4 a1 = *(const float4*)(Ap1 + e);

        acc0.x = fmaf(a0.x, w0.x, acc0.x); acc0.y = fmaf(a0.x, w0.y, acc0.y);
        acc0.z = fmaf(a0.x, w0.z, acc0.z); acc0.w = fmaf(a0.x, w0.w, acc0.w);
        acc1.x = fmaf(a1.x, w0.x, acc1.x); acc1.y = fmaf(a1.x, w0.y, acc1.y);
        acc1.z = fmaf(a1.x, w0.z, acc1.z); acc1.w = fmaf(a1.x, w0.w, acc1.w);

        acc0.x = fmaf(a0.y, w1.x, acc0.x); acc0.y = fmaf(a0.y, w1.y, acc0.y);
        acc0.z = fmaf(a0.y, w1.z, acc0.z); acc0.w = fmaf(a0.y, w1.w, acc0.w);
        acc1.x = fmaf(a1.y, w1.x, acc1.x); acc1.y = fmaf(a1.y, w1.y, acc1.y);
        acc1.z = fmaf(a1.y, w1.z, acc1.z); acc1.w = fmaf(a1.y, w1.w, acc1.w);

        acc0.x = fmaf(a0.z, w2.x, acc0.x); acc0.y = fmaf(a0.z, w2.y, acc0.y);
        acc0.z = fmaf(a0.z, w2.z, acc0.z); acc0.w = fmaf(a0.z, w2.w, acc0.w);
        acc1.x = fmaf(a1.z, w2.x, acc1.x); acc1.y = fmaf(a1.z, w2.y, acc1.y);
        acc1.z = fmaf(a1.z, w2.z, acc1.z); acc1.w = fmaf(a1.z, w2.w, acc1.w);

        acc0.x = fmaf(a0.w, w3.x, acc0.x); acc0.y = fmaf(a0.w, w3.y, acc0.y);
        acc0.z = fmaf(a0.w, w3.z, acc0.z); acc0.w = fmaf(a0.w, w3.w, acc0.w);
        acc1.x = fmaf(a1.w, w3.x, acc1.x); acc1.y = fmaf(a1.w, w3.y, acc1.y);
        acc1.z = fmaf(a1.w, w3.z, acc1.z); acc1.w = fmaf(a1.w, w3.w, acc1.w);
    }

    if (m == 0) {
        const float4 bb = *(const float4*)(bq + d0);
        float4 o0, o1;
        o0.x = tanh_fast(acc0.x + bb.x); o0.y = tanh_fast(acc0.y + bb.y);
        o0.z = tanh_fast(acc0.z + bb.z); o0.w = tanh_fast(acc0.w + bb.w);
        o1.x = tanh_fast(acc1.x + bb.x); o1.y = tanh_fast(acc1.y + bb.y);
        o1.z = tanh_fast(acc1.z + bb.z); o1.w = tanh_fast(acc1.w + bb.w);
        *(float4*)(ws + TAOFF + (size_t)row0 * DD + d0)       = o0;
        *(float4*)(ws + TAOFF + (size_t)(row0 + 1) * DD + d0) = o1;
    } else if (m == 1) {
        float4 o0, o1;
        o0.x = tanh_fast(acc0.x); o0.y = tanh_fast(acc0.y);
        o0.z = tanh_fast(acc0.z); o0.w = tanh_fast(acc0.w);
        o1.x = tanh_fast(acc1.x); o1.y = tanh_fast(acc1.y);
        o1.z = tanh_fast(acc1.z); o1.w = tanh_fast(acc1.w);
        const int b  = (row0 >= SS) ? 1 : 0;
        const int sl = row0 - b * SS;
        // tbT4 float index: (((b*128 + e4)*400) + s) * 4, e4 = d0/4
        float* p = ws + TBT4OFF + (((size_t)b * 128 + (d0 >> 2)) * SS + sl) * 4;
        *(float4*)p       = o0;   // s = sl
        *(float4*)(p + 4) = o1;   // s = sl+1
    } else if (m == 2) {
        *(float4*)(ws + MOFF + (size_t)row0 * DD + d0)       = acc0;
        *(float4*)(ws + MOFF + (size_t)(row0 + 1) * DD + d0) = acc1;
    } else {
        const float4 bb = *(const float4*)(bout + d0);
        const int b  = (row0 >= SS) ? 1 : 0;
        const int tb = row0 - b * SS;
        float4 o0, o1;
        o0.x = acc0.x + bb.x; o0.y = acc0.y + bb.y;
        o0.z = acc0.z + bb.z; o0.w = acc0.w + bb.w;
        o1.x = acc1.x + bb.x; o1.y = acc1.y + bb.y;
        o1.z = acc1.z + bb.z; o1.w = acc1.w + bb.w;
        *(float4*)(out0 + ((size_t)(tb * BB + b)) * DD + d0)       = o0;
        *(float4*)(out0 + ((size_t)((tb + 1) * BB + b)) * DD + d0) = o1;
    }
}

// ---------------------------------------------------------------------------
// K2: tanh-identity scores + dual softmax. Block = (b, t-pair), 448 thr = s.
// score(t,s) = sum_e v[e] * (ta[t][e]+Tb[e][s]) / (1 + ta[t][e]*Tb[e][s])
// Tb read as float4-packed tbT4 (4 e's per 16B coalesced load).
// ---------------------------------------------------------------------------
__global__ __launch_bounds__(448) void k2_attn(
    const float* __restrict__ ws, const float* __restrict__ v,
    const int* __restrict__ lens, float* __restrict__ align_out)
{
    const int pair = blockIdx.x;           // 0..399
    const int b    = pair / 200;
    const int t0   = (pair - b * 200) * 2;
    const int t1   = t0 + 1;
    const int tid  = threadIdx.x;
    const int s    = tid;
    const int sidx = (s < SS) ? s : 0;
    const int len  = lens[b];

    const float4* __restrict__ tb4 =
        (const float4*)(ws + TBT4OFF) + (size_t)b * 128 * SS + sidx;
    const float* __restrict__ ta0 = ws + TAOFF + ((size_t)(b * SS + t0)) * DD;
    const float* __restrict__ ta1 = ta0 + DD;

    float accA0 = 0.f, accB0 = 0.f, accA1 = 0.f, accB1 = 0.f;
    #pragma unroll 4
    for (int e4 = 0; e4 < 128; ++e4) {
        const float4 tb = tb4[(size_t)e4 * SS];
        const int e = e4 * 4;
        {
            const float a0 = ta0[e], a1 = ta1[e], vv = v[e];
            const float r0 = RCPF(fmaf(a0, tb.x, 1.f));
            const float r1 = RCPF(fmaf(a1, tb.x, 1.f));
            accA0 = fmaf(vv, (a0 + tb.x) * r0, accA0);
            accA1 = fmaf(vv, (a1 + tb.x) * r1, accA1);
        }
        {
            const float a0 = ta0[e + 1], a1 = ta1[e + 1], vv = v[e + 1];
            const float r0 = RCPF(fmaf(a0, tb.y, 1.f));
            const float r1 = RCPF(fmaf(a1, tb.y, 1.f));
            accB0 = fmaf(vv, (a0 + tb.y) * r0, accB0);
            accB1 = fmaf(vv, (a1 + tb.y) * r1, accB1);
        }
        {
            const float a0 = ta0[e + 2], a1 = ta1[e + 2], vv = v[e + 2];
            const float r0 = RCPF(fmaf(a0, tb.z, 1.f));
            const float r1 = RCPF(fmaf(a1, tb.z, 1.f));
            accA0 = fmaf(vv, (a0 + tb.z) * r0, accA0);
            accA1 = fmaf(vv, (a1 + tb.z) * r1, accA1);
        }
        {
            const float a0 = ta0[e + 3], a1 = ta1[e + 3], vv = v[e + 3];
            const float r0 = RCPF(fmaf(a0, tb.w, 1.f));
            const float r1 = RCPF(fmaf(a1, tb.w, 1.f));
            accB0 = fmaf(vv, (a0 + tb.w) * r0, accB0);
            accB1 = fmaf(vv, (a1 + tb.w) * r1, accB1);
        }
    }

    const bool v0 = (s < SS) && (s < len) && (s != t0);
    const bool v1 = (s < SS) && (s < len) && (s != t1);
    const float sc0 = v0 ? (accA0 + accB0) : -INFINITY;
    const float sc1 = v1 ? (accA1 + accB1) : -INFINITY;

    __shared__ float wred0[8], wred1[8];
    const int wid  = tid >> 6;
    const int lane = tid & 63;

    float m0 = sc0, m1 = sc1;
    #pragma unroll
    for (int off = 32; off > 0; off >>= 1) {
        m0 = fmaxf(m0, __shfl_xor(m0, off));
        m1 = fmaxf(m1, __shfl_xor(m1, off));
    }
    if (lane == 0) { wred0[wid] = m0; wred1[wid] = m1; }
    __syncthreads();
    float mx0 = wred0[0], mx1 = wred1[0];
    #pragma unroll
    for (int w = 1; w < 7; ++w) {
        mx0 = fmaxf(mx0, wred0[w]);
        mx1 = fmaxf(mx1, wred1[w]);
    }
    __syncthreads();

    const float p0 = v0 ? __expf(sc0 - mx0) : 0.f;
    const float p1 = v1 ? __expf(sc1 - mx1) : 0.f;
    float s0v = p0, s1v = p1;
    #pragma unroll
    for (int off = 32; off > 0; off >>= 1) {
        s0v += __shfl_xor(s0v, off);
        s1v += __shfl_xor(s1v, off);
    }
    if (lane == 0) { wred0[wid] = s0v; wred1[wid] = s1v; }
    __syncthreads();
    float tot0 = wred0[0], tot1 = wred1[0];
    #pragma unroll
    for (int w = 1; w < 7; ++w) { tot0 += wred0[w]; tot1 += wred1[w]; }
    const float inv0 = RCPF(tot0);
    const float inv1 = RCPF(tot1);

    if (s < SS) {
        align_out[((size_t)(t0 * BB) + b) * SS + s] = p0 * inv0;
        align_out[((size_t)(t1 * BB) + b) * SS + s] = p1 * inv1;
    }
}

// ---------------------------------------------------------------------------
// K3: out0[t,b,d] += sum_{s chunk} align[t,b,s] * M[b,s,d]; s unrolled x4.
// Grid (2,100,4) = 800 blocks; small-volume fp32 HW atomics onto P-init out0.
// ---------------------------------------------------------------------------
__global__ __launch_bounds__(256) void k3_out(
    const float* __restrict__ ws, const float* __restrict__ align_out,
    float* __restrict__ out0)
{
    const int d     = blockIdx.x * 256 + threadIdx.x;
    const int r0    = blockIdx.y * 8;
    const int s0    = blockIdx.z * 100;
    const int b     = (r0 >= SS) ? 1 : 0;
    const int tbase = r0 - b * SS;

    const float* __restrict__ Mb = ws + MOFF + (size_t)b * SS * DD;

    float acc[8];
    #pragma unroll
    for (int j = 0; j < 8; ++j) acc[j] = 0.f;

    for (int s = s0; s < s0 + 100; s += 4) {
        float4 al[8];
        #pragma unroll
        for (int j = 0; j < 8; ++j)
            al[j] = *(const float4*)(align_out + ((size_t)((tbase + j) * BB) + b) * SS + s);
        const float mv0 = Mb[(size_t)(s + 0) * DD + d];
        const float mv1 = Mb[(size_t)(s + 1) * DD + d];
        const float mv2 = Mb[(size_t)(s + 2) * DD + d];
        const float mv3 = Mb[(size_t)(s + 3) * DD + d];
        #pragma unroll
        for (int j = 0; j < 8; ++j) {
            acc[j] = fmaf(al[j].x, mv0, acc[j]);
            acc[j] = fmaf(al[j].y, mv1, acc[j]);
            acc[j] = fmaf(al[j].z, mv2, acc[j]);
            acc[j] = fmaf(al[j].w, mv3, acc[j]);
        }
    }

    #pragma unroll
    for (int j = 0; j < 8; ++j)
        unsafeAtomicAdd(&out0[((size_t)((tbase + j) * BB) + b) * DD + d], acc[j]);
}

// ---------------------------------------------------------------------------
extern "C" void kernel_launch(void* const* d_in, const int* in_sizes, int n_in,
                              void* d_out, int out_size, void* d_ws, size_t ws_size,
                              hipStream_t stream)
{
    const float* input = (const float*)d_in[0];
    const float* mb    = (const float*)d_in[1];
    const int*   lens  = (const int*)d_in[2];
    const float* Wq    = (const float*)d_in[3];
    const float* bq    = (const float*)d_in[4];
    const float* Wc    = (const float*)d_in[5];
    const float* v     = (const float*)d_in[6];
    const float* Wout  = (const float*)d_in[7];
    const float* bout  = (const float*)d_in[8];

    float* out0 = (float*)d_out;               // [T,B,D] = 409600
    float* out1 = out0 + (size_t)BB * SS * DD; // [T,B,S] = 320000
    float* ws   = (float*)d_ws;

    hipLaunchKernelGGL(k1_gemm, dim3(50, 4, 4), dim3(256), 0, stream,
                       input, mb, Wq, bq, Wc, Wout, bout, ws, out0);
    hipLaunchKernelGGL(k2_attn, dim3(400), dim3(448), 0, stream,
                       ws, v, lens, out1);
    hipLaunchKernelGGL(k3_out, dim3(2, 100, 4), dim3(256), 0, stream,
                       ws, out1, out0);
}

// Round 5
// 199.041 us; speedup vs baseline: 1.3378x; 1.0908x over previous
//
#include <hip/hip_runtime.h>
#include <math.h>

// Problem constants (reference: B=2, S=T=400, D=512)
#define BB 2
#define SS 400
#define DD 512
#define TWO_LOG2E 2.8853900817779268f   // tanh(x) = 1 - 2/(exp2(TWO_LOG2E*x)+1)

#if __has_builtin(__builtin_amdgcn_exp2f)
#define EXP2F(x) __builtin_amdgcn_exp2f(x)
#else
#define EXP2F(x) exp2f(x)
#endif
#define RCPF(x) __builtin_amdgcn_rcpf(x)

// Workspace float layout:
//   ta   [0,       409600) : tanh(input@Wq + bq)                  [B,T,D]
//   M    [409600,  819200) : mb@Wout_top                          [B,S,D]
//   tbT4 [819200, 1228800) : tanh(mb@Wc), packed [B][D/4][S][4]
//   part [1228800,1868800) : partial scores, [eh][B][T][S] (2x320000)
// out0 gets input@Wout_bot + bout from k1 (m==3); k3 adds align@M in-place.
#define TAOFF 0
#define MOFF 409600
#define TBT4OFF 819200
#define PARTOFF 1228800

__device__ __forceinline__ float tanh_fast(float x) {
    return fmaf(-2.f, RCPF(EXP2F(TWO_LOG2E * x) + 1.f), 1.f);
}

// ---------------------------------------------------------------------------
// K1: four GEMMs (800x512x512). Grid (100 rowgroups, 1, 4 gemms), 256 thr.
// Block tile: 8 rows x 512 cols; thread = 8 rows x 2 cols (16 acc).
// W loads: float2, coalesced (wave covers 128 contiguous cols).
// A loads: wave-uniform float4 (all lanes same addr -> broadcast/scalar).
// 2-phase hand-pipelined K loop (prefetch next 4 k while FMAing current).
// W vector-path demand: 0.5 B/FMA -> ~420 MB total ~ FMA floor.
// ---------------------------------------------------------------------------
__global__ __launch_bounds__(256) void k1_gemm(
    const float* __restrict__ input, const float* __restrict__ mb,
    const float* __restrict__ Wq, const float* __restrict__ bq,
    const float* __restrict__ Wc, const float* __restrict__ Wout,
    const float* __restrict__ bout, float* __restrict__ ws,
    float* __restrict__ out0)
{
    const int d0 = threadIdx.x * 2;          // 0..510
    const int r0 = blockIdx.x * 8;           // row base (8 rows, uniform)
    const int m  = blockIdx.z;

    const float* __restrict__ A = (m == 0 || m == 3) ? input : mb;
    const float* __restrict__ W =
        (m == 0) ? Wq : (m == 1) ? Wc : (m == 2) ? Wout : Wout + DD * DD;

    const float* __restrict__ Ab = A + (size_t)r0 * DD;
    const float* __restrict__ Wp = W + d0;

    float2 acc[8];
    #pragma unroll
    for (int r = 0; r < 8; ++r) acc[r] = make_float2(0.f, 0.f);

    float4 aA[8], aB[8];
    float2 wA[4], wB[4];

    auto LOAD = [&](float4 (&aa)[8], float2 (&ww)[4], int ee) {
        #pragma unroll
        for (int r = 0; r < 8; ++r)
            aa[r] = *(const float4*)(Ab + (size_t)r * DD + ee);
        #pragma unroll
        for (int j = 0; j < 4; ++j)
            ww[j] = *(const float2*)(Wp + (size_t)(ee + j) * DD);
    };
    auto FMA4 = [&](const float4 (&aa)[8], const float2 (&ww)[4]) {
        #pragma unroll
        for (int j = 0; j < 4; ++j) {
            #pragma unroll
            for (int r = 0; r < 8; ++r) {
                const float av = (j == 0) ? aa[r].x : (j == 1) ? aa[r].y
                               : (j == 2) ? aa[r].z : aa[r].w;
                acc[r].x = fmaf(av, ww[j].x, acc[r].x);
                acc[r].y = fmaf(av, ww[j].y, acc[r].y);
            }
        }
    };

    LOAD(aA, wA, 0);
    for (int e = 0; e < DD; e += 8) {
        LOAD(aB, wB, e + 4);
        FMA4(aA, wA);
        if (e + 8 < DD) LOAD(aA, wA, e + 8);
        FMA4(aB, wB);
    }

    if (m == 0) {
        const float b0 = bq[d0], b1 = bq[d0 + 1];
        #pragma unroll
        for (int r = 0; r < 8; ++r) {
            float2 o;
            o.x = tanh_fast(acc[r].x + b0);
            o.y = tanh_fast(acc[r].y + b1);
            *(float2*)(ws + TAOFF + (size_t)(r0 + r) * DD + d0) = o;
        }
    } else if (m == 1) {
        const int b   = (r0 >= SS) ? 1 : 0;
        const int sl0 = r0 - b * SS;
        // tbT4 flat idx: ((b*128 + d/4)*400 + s)*4 + (d&3)
        #pragma unroll
        for (int c = 0; c < 2; ++c) {
            const int d  = d0 + c;
            float* base = ws + TBT4OFF +
                (size_t)(((b * 128 + (d >> 2)) * SS + sl0) * 4 + (d & 3));
            #pragma unroll
            for (int r = 0; r < 8; ++r)
                base[r * 4] = tanh_fast(c == 0 ? acc[r].x : acc[r].y);
        }
    } else if (m == 2) {
        #pragma unroll
        for (int r = 0; r < 8; ++r)
            *(float2*)(ws + MOFF + (size_t)(r0 + r) * DD + d0) = acc[r];
    } else {
        const float b0 = bout[d0], b1 = bout[d0 + 1];
        const int b  = (r0 >= SS) ? 1 : 0;
        const int tb = r0 - b * SS;
        #pragma unroll
        for (int r = 0; r < 8; ++r) {
            float2 o;
            o.x = acc[r].x + b0;
            o.y = acc[r].y + b1;
            *(float2*)(out0 + ((size_t)((tb + r) * BB + b)) * DD + d0) = o;
        }
    }
}

// ---------------------------------------------------------------------------
// K2a: partial scores over an e-half. Grid (200 t-pairs, 2 b, 2 eh), 448 thr.
// thread = s. score_part(t,s) = sum_e v[e]*(ta+tb)/(1+ta*tb)   (tanh identity)
// tb: float4-packed coalesced; ta/v: block-uniform scalar path.
// ---------------------------------------------------------------------------
__global__ __launch_bounds__(448) void k2a_score(
    const float* __restrict__ ws, const float* __restrict__ v,
    float* __restrict__ part)
{
    const int tp = blockIdx.x;            // 0..199
    const int b  = blockIdx.y;
    const int eh = blockIdx.z;
    const int t0 = tp * 2;
    const int t1 = t0 + 1;
    const int s  = threadIdx.x;
    const int sidx = (s < SS) ? s : 0;
    const int e0 = eh * 256;

    const float4* __restrict__ tb4 =
        (const float4*)(ws + TBT4OFF) + ((size_t)b * 128 + (e0 >> 2)) * SS + sidx;
    const float* __restrict__ ta0 = ws + TAOFF + ((size_t)(b * SS + t0)) * DD + e0;
    const float* __restrict__ ta1 = ta0 + DD;
    const float* __restrict__ vp  = v + e0;

    float acc0A = 0.f, acc0B = 0.f, acc1A = 0.f, acc1B = 0.f;
    #pragma unroll 4
    for (int e4 = 0; e4 < 64; ++e4) {
        const float4 tb = tb4[(size_t)e4 * SS];
        const int e = e4 * 4;
        {
            const float a0 = ta0[e], a1 = ta1[e], vv = vp[e];
            const float r0 = RCPF(fmaf(a0, tb.x, 1.f));
            const float r1 = RCPF(fmaf(a1, tb.x, 1.f));
            acc0A = fmaf(vv, (a0 + tb.x) * r0, acc0A);
            acc1A = fmaf(vv, (a1 + tb.x) * r1, acc1A);
        }
        {
            const float a0 = ta0[e + 1], a1 = ta1[e + 1], vv = vp[e + 1];
            const float r0 = RCPF(fmaf(a0, tb.y, 1.f));
            const float r1 = RCPF(fmaf(a1, tb.y, 1.f));
            acc0B = fmaf(vv, (a0 + tb.y) * r0, acc0B);
            acc1B = fmaf(vv, (a1 + tb.y) * r1, acc1B);
        }
        {
            const float a0 = ta0[e + 2], a1 = ta1[e + 2], vv = vp[e + 2];
            const float r0 = RCPF(fmaf(a0, tb.z, 1.f));
            const float r1 = RCPF(fmaf(a1, tb.z, 1.f));
            acc0A = fmaf(vv, (a0 + tb.z) * r0, acc0A);
            acc1A = fmaf(vv, (a1 + tb.z) * r1, acc1A);
        }
        {
            const float a0 = ta0[e + 3], a1 = ta1[e + 3], vv = vp[e + 3];
            const float r0 = RCPF(fmaf(a0, tb.w, 1.f));
            const float r1 = RCPF(fmaf(a1, tb.w, 1.f));
            acc0B = fmaf(vv, (a0 + tb.w) * r0, acc0B);
            acc1B = fmaf(vv, (a1 + tb.w) * r1, acc1B);
        }
    }

    if (s < SS) {
        float* __restrict__ pp = part + (size_t)eh * 320000;
        pp[((size_t)(b * SS + t0)) * SS + s] = acc0A + acc0B;
        pp[((size_t)(b * SS + t1)) * SS + s] = acc1A + acc1B;
    }
}

// ---------------------------------------------------------------------------
// K2b: combine partials, mask, softmax, write align [T,B,S]. Grid 800, 448 thr.
// ---------------------------------------------------------------------------
__global__ __launch_bounds__(448) void k2b_softmax(
    const float* __restrict__ part, const int* __restrict__ lens,
    float* __restrict__ align_out)
{
    const int bt = blockIdx.x;            // b*SS + t
    const int b  = bt / SS;
    const int t  = bt - b * SS;
    const int tid = threadIdx.x;
    const int s   = tid;
    const int len = lens[b];

    float sc = -INFINITY;
    bool valid = false;
    if (s < SS) {
        valid = (s < len) && (s != t);
        if (valid)
            sc = part[(size_t)bt * SS + s] + part[(size_t)320000 + (size_t)bt * SS + s];
    }

    __shared__ float wred[8];
    const int wid  = tid >> 6;
    const int lane = tid & 63;

    float m = sc;
    #pragma unroll
    for (int off = 32; off > 0; off >>= 1) m = fmaxf(m, __shfl_xor(m, off));
    if (lane == 0) wred[wid] = m;
    __syncthreads();
    float mx = wred[0];
    #pragma unroll
    for (int w = 1; w < 7; ++w) mx = fmaxf(mx, wred[w]);
    __syncthreads();

    const float p = valid ? __expf(sc - mx) : 0.f;
    float sm = p;
    #pragma unroll
    for (int off = 32; off > 0; off >>= 1) sm += __shfl_xor(sm, off);
    if (lane == 0) wred[wid] = sm;
    __syncthreads();
    float tot = wred[0];
    #pragma unroll
    for (int w = 1; w < 7; ++w) tot += wred[w];
    const float inv = RCPF(tot);

    if (s < SS) align_out[((size_t)(t * BB) + b) * SS + s] = p * inv;
}

// ---------------------------------------------------------------------------
// K3: out0[t,b,d] += sum_s align[t,b,s] * M[b,s,d]. Grid (2,100), 256 thr.
// Thread = 8 t-rows x 1 d col; full s per block (no atomics). 2-phase
// prefetch: M coalesced dwords, align block-uniform float4s.
// ---------------------------------------------------------------------------
__global__ __launch_bounds__(256) void k3_out(
    const float* __restrict__ ws, const float* __restrict__ align_out,
    float* __restrict__ out0)
{
    const int d     = blockIdx.x * 256 + threadIdx.x;
    const int r0    = blockIdx.y * 8;
    const int b     = (r0 >= SS) ? 1 : 0;
    const int tbase = r0 - b * SS;

    const float* __restrict__ Mb = ws + MOFF + (size_t)b * SS * DD;

    // P prefetch (out0 currently holds input@Wout_bot + bout)
    float pv[8];
    #pragma unroll
    for (int j = 0; j < 8; ++j)
        pv[j] = out0[((size_t)((tbase + j) * BB) + b) * DD + d];

    float acc[8];
    #pragma unroll
    for (int j = 0; j < 8; ++j) acc[j] = 0.f;

    float mA[4], mB[4];
    float4 alA[8], alB[8];

    auto LOAD = [&](float (&mm)[4], float4 (&al)[8], int s) {
        #pragma unroll
        for (int i = 0; i < 4; ++i)
            mm[i] = Mb[(size_t)(s + i) * DD + d];
        #pragma unroll
        for (int j = 0; j < 8; ++j)
            al[j] = *(const float4*)(align_out +
                     ((size_t)((tbase + j) * BB) + b) * SS + s);
    };
    auto FMA4 = [&](const float (&mm)[4], const float4 (&al)[8]) {
        #pragma unroll
        for (int j = 0; j < 8; ++j) {
            acc[j] = fmaf(al[j].x, mm[0], acc[j]);
            acc[j] = fmaf(al[j].y, mm[1], acc[j]);
            acc[j] = fmaf(al[j].z, mm[2], acc[j]);
            acc[j] = fmaf(al[j].w, mm[3], acc[j]);
        }
    };

    LOAD(mA, alA, 0);
    for (int s = 0; s < SS; s += 8) {
        LOAD(mB, alB, s + 4);
        FMA4(mA, alA);
        if (s + 8 < SS) LOAD(mA, alA, s + 8);
        FMA4(mB, alB);
    }

    #pragma unroll
    for (int j = 0; j < 8; ++j)
        out0[((size_t)((tbase + j) * BB) + b) * DD + d] = acc[j] + pv[j];
}

// ---------------------------------------------------------------------------
extern "C" void kernel_launch(void* const* d_in, const int* in_sizes, int n_in,
                              void* d_out, int out_size, void* d_ws, size_t ws_size,
                              hipStream_t stream)
{
    const float* input = (const float*)d_in[0];
    const float* mb    = (const float*)d_in[1];
    const int*   lens  = (const int*)d_in[2];
    const float* Wq    = (const float*)d_in[3];
    const float* bq    = (const float*)d_in[4];
    const float* Wc    = (const float*)d_in[5];
    const float* v     = (const float*)d_in[6];
    const float* Wout  = (const float*)d_in[7];
    const float* bout  = (const float*)d_in[8];

    float* out0 = (float*)d_out;               // [T,B,D] = 409600
    float* out1 = out0 + (size_t)BB * SS * DD; // [T,B,S] = 320000
    float* ws   = (float*)d_ws;

    hipLaunchKernelGGL(k1_gemm, dim3(100, 1, 4), dim3(256), 0, stream,
                       input, mb, Wq, bq, Wc, Wout, bout, ws, out0);
    hipLaunchKernelGGL(k2a_score, dim3(200, 2, 2), dim3(448), 0, stream,
                       ws, v, ws + PARTOFF);
    hipLaunchKernelGGL(k2b_softmax, dim3(800), dim3(448), 0, stream,
                       ws + PARTOFF, lens, out1);
    hipLaunchKernelGGL(k3_out, dim3(2, 100), dim3(256), 0, stream,
                       ws, out1, out0);
}